// Round 9
// baseline (146.448 us; speedup 1.0000x reference)
//
#include <hip/hip_runtime.h>
#include <hip/hip_bf16.h>

#define SEQ 81
#define DIM 64
#define NT  384          // 6 waves
#define NW  6
#define LDK 68           // sK row stride in shorts (136 B, 8B-aligned; ~2-way = free)
#define LDV 102          // sVt row stride in shorts (204 B, odd-dword all-bank spread)
#define LDP 102          // sP row stride in shorts

typedef short bf16x8 __attribute__((ext_vector_type(8)));
typedef short bf16x4 __attribute__((ext_vector_type(4)));
typedef float f32x4  __attribute__((ext_vector_type(4)));

static constexpr float kS2 = 0.0520587716f;   // log2(e) / sqrt(768) — folded scale

__device__ __forceinline__ short f2bf(float f) {
    __hip_bfloat16 h = __float2bfloat16(f);
    return __builtin_bit_cast(short, h);
}
__device__ __forceinline__ float bf2f(short h) {
    unsigned u = ((unsigned)(unsigned short)h) << 16;
    return __builtin_bit_cast(float, u);
}
__device__ __forceinline__ bf16x8 cat8(bf16x4 a, bf16x4 b) {
    bf16x8 r;
    r[0]=a[0]; r[1]=a[1]; r[2]=a[2]; r[3]=a[3];
    r[4]=b[0]; r[5]=b[1]; r[6]=b[2]; r[7]=b[3];
    return r;
}

__global__ void emb_cvt_kernel(const float* __restrict__ in, short* __restrict__ out, int n) {
    int i = blockIdx.x * 256 + threadIdx.x;
    if (i < n) out[i] = f2bf(in[i]);
}

// Swapped-operand MFMAs: lane owns row i = 16w + (lane&15), and 4 consecutive
// {j|d} = 16nt + 4*(lane>>4) + r.  K staged LDS (2 barriers); emb staged bf16 in
// d_ws by prologue (21 KB -> L1-resident); Qe prefetched pre-bar1, scattered post-bar2.
__global__ __launch_bounds__(NT, 8)
void rpsa_kernel(const float* __restrict__ Q, const float* __restrict__ K,
                 const float* __restrict__ V, const short* __restrict__ embw,
                 const int* __restrict__ ucp, float* __restrict__ out)
{
    extern __shared__ char smraw[];
    short* sVt = (short*)smraw;              // [64][102]  13056 B (V^T, bf16)
    short* sK  = (short*)(smraw + 13056);    // [96][68]   13056 B (bf16)
    short* sP  = (short*)(smraw + 13056);    // [96][102]  19584 B bias/P, overlays sK
    // total 32640 B -> 5 blocks/CU

    const int tid = threadIdx.x;
    const size_t base = (size_t)blockIdx.x * (SEQ * DIM);
    const int uc = ucp[0];
    const int w  = tid >> 6, L = tid & 63;
    const int lr = L & 15,  lg = L >> 4;
    const int iRow = 16*w + lr;              // lane's own row

    // ---- Q B-fragment from global, pre-scaled by log2e/sqrt(768) ----
    bf16x8 aq0, aq1;
    {
        const int qrow = (iRow < SEQ) ? iRow : (SEQ - 1);   // clamp pad lanes
        const float* qp = Q + base + qrow*DIM + 8*lg;
        const f32x4 q0 = *(const f32x4*)(qp);
        const f32x4 q1 = *(const f32x4*)(qp + 4);
        const f32x4 q2 = *(const f32x4*)(qp + 32);
        const f32x4 q3 = *(const f32x4*)(qp + 36);
        #pragma unroll
        for (int t = 0; t < 4; ++t) {
            aq0[t]   = f2bf(q0[t]*kS2);
            aq0[4+t] = f2bf(q1[t]*kS2);
            aq1[t]   = f2bf(q2[t]*kS2);
            aq1[4+t] = f2bf(q3[t]*kS2);
        }
    }

    // ---- stage K bf16 (rows >= 81 zeroed) ----
    for (int u = tid; u < 96 * DIM / 8; u += NT) {        // 2 iters
        const int row = u >> 3, so = (u & 7) * 8;
        bf16x4 lo = {0,0,0,0}, hi = {0,0,0,0};
        if (row < SEQ) {
            const f32x4 k0 = *(const f32x4*)(K + base + row*DIM + so);
            const f32x4 k1 = *(const f32x4*)(K + base + row*DIM + so + 4);
            #pragma unroll
            for (int t = 0; t < 4; ++t) { lo[t] = f2bf(k0[t]); hi[t] = f2bf(k1[t]); }
        }
        *(bf16x4*)(sK + row*LDK + so)     = lo;
        *(bf16x4*)(sK + row*LDK + so + 4) = hi;
    }
    // ---- stage V transposed (4x4 register transpose; cols j>=81 zeroed) ----
    {
        const int j4 = tid >> 4;          // 0..23
        const int d4 = tid & 15;          // 0..15
        f32x4 rw[4];
        #pragma unroll
        for (int e = 0; e < 4; ++e) {
            const int j = 4*j4 + e;
            rw[e] = (j < SEQ) ? *(const f32x4*)(V + base + j*DIM + 4*d4)
                              : (f32x4){0.f,0.f,0.f,0.f};
        }
        #pragma unroll
        for (int c = 0; c < 4; ++c) {
            const int d = 4*d4 + c;
            bf16x4 pv = { f2bf(rw[0][c]), f2bf(rw[1][c]), f2bf(rw[2][c]), f2bf(rw[3][c]) };
            *(bf16x4*)(sVt + d*LDV + 4*j4) = pv;
        }
    }

    // ---- Qe pass-1 prefetch (embw bf16, L1-resident; no LDS needed) ----
    // lane gets Qe[iRow][rel = 80 + 16nt2 + 4lg + r]; scatter deferred to post-bar2.
    bf16x4 qe[NW];
    #pragma unroll
    for (int nt2 = 0; nt2 < NW; ++nt2) {
        if (nt2 > w) continue;
        int erow = 80 + 16*nt2 + lr;
        if (erow > 2*SEQ) erow = 2*SEQ;          // clamp: affects only pad rows (i>80)
        bf16x8 e0 = *(const bf16x8*)(embw + erow*DIM + 8*lg);
        bf16x8 e1 = *(const bf16x8*)(embw + erow*DIM + 32 + 8*lg);
        f32x4 a = {0.f,0.f,0.f,0.f};
        a = __builtin_amdgcn_mfma_f32_16x16x32_bf16(e0, aq0, a, 0, 0, 0);
        a = __builtin_amdgcn_mfma_f32_16x16x32_bf16(e1, aq1, a, 0, 0, 0);
        bf16x4 p = { f2bf(a[0]), f2bf(a[1]), f2bf(a[2]), f2bf(a[3]) };
        qe[nt2] = p;
    }
    __syncthreads();   // bar1

    // ---- QK^T from sK: accs[nt][r] = S[iRow][j = 16nt + 4lg + r] ----
    f32x4 accs[NW] = {};
    const int ntEnd = uc ? w : (NW - 1);
    __builtin_amdgcn_s_setprio(1);
    #pragma unroll
    for (int nt = 0; nt < NW; ++nt) {
        if (nt > ntEnd) continue;
        const int kr = 16*nt + lr;
        bf16x8 b0 = cat8(*(const bf16x4*)(sK + kr*LDK + 8*lg),
                         *(const bf16x4*)(sK + kr*LDK + 8*lg + 4));
        bf16x8 b1 = cat8(*(const bf16x4*)(sK + kr*LDK + 32 + 8*lg),
                         *(const bf16x4*)(sK + kr*LDK + 32 + 8*lg + 4));
        f32x4 a = accs[nt];
        a = __builtin_amdgcn_mfma_f32_16x16x32_bf16(b0, aq0, a, 0, 0, 0);
        a = __builtin_amdgcn_mfma_f32_16x16x32_bf16(b1, aq1, a, 0, 0, 0);
        accs[nt] = a;
    }
    __builtin_amdgcn_s_setprio(0);
    __syncthreads();   // bar2: sK dead -> sP overlay live

    // ---- scatter prefetched pass-1 bias into sP (rows = own band -> race-free) ----
    #pragma unroll
    for (int nt2 = 0; nt2 < NW; ++nt2) {
        if (nt2 > w) continue;
        #pragma unroll
        for (int r = 0; r < 4; ++r) {
            const int j = 16*(w - nt2) + lr - 4*lg - r;   // j = iRow - (rel-80)
            if (j >= 0) sP[iRow*LDP + j] = qe[nt2][r];
        }
    }
    // ---- pass-0 (non-causal only): rel in [i,79], j = 80+i-rel > i ----
    if (!uc) {
        #pragma unroll
        for (int nt2 = 0; nt2 < NW - 1; ++nt2) {
            if (nt2 < w) continue;
            const int erow = 16*nt2 + lr;        // <= 79
            bf16x8 e0 = *(const bf16x8*)(embw + erow*DIM + 8*lg);
            bf16x8 e1 = *(const bf16x8*)(embw + erow*DIM + 32 + 8*lg);
            f32x4 a = {0.f,0.f,0.f,0.f};
            a = __builtin_amdgcn_mfma_f32_16x16x32_bf16(e0, aq0, a, 0, 0, 0);
            a = __builtin_amdgcn_mfma_f32_16x16x32_bf16(e1, aq1, a, 0, 0, 0);
            #pragma unroll
            for (int r = 0; r < 4; ++r) {
                const int rel = 16*nt2 + 4*lg + r;
                if (rel >= iRow) sP[iRow*LDP + (80 + iRow - rel)] = f2bf(a[r]);
            }
        }
    }
    // No barrier: each wave's bias slots are produced and consumed by the same wave.

    // ---- fused softmax (no max-subtraction; scores bounded) ----
    const int jmax = uc ? ((iRow < SEQ-1) ? iRow : SEQ-1) : (SEQ-1);
    float sum = 0.f;
    #pragma unroll
    for (int nt = 0; nt < NW; ++nt) {
        short* slot = sP + iRow*LDP + 16*nt + 4*lg;
        if (nt <= ntEnd) {
            bf16x4 bias = *(const bf16x4*)(slot);
            bf16x4 p;
            #pragma unroll
            for (int r = 0; r < 4; ++r) {
                const int j = 16*nt + 4*lg + r;
                const float x = accs[nt][r] + bf2f(bias[r]);
                const float e = (j <= jmax) ? exp2f(x) : 0.f;
                sum += e;
                p[r] = f2bf(e);
            }
            *(bf16x4*)(slot) = p;
        } else {
            *(bf16x4*)(slot) = (bf16x4){0,0,0,0};   // dead causal tiles -> P = 0
        }
    }
    sum += __shfl_xor(sum, 16);
    sum += __shfl_xor(sum, 32);
    const float inv = 1.f / sum;

    // ---- PV: lane gets O[iRow][d = 16nt + 4lg + r] ----
    bf16x8 ap0, ap1, ap2;
    ap0 = cat8(*(const bf16x4*)(sP + iRow*LDP + 8*lg),
               *(const bf16x4*)(sP + iRow*LDP + 8*lg + 4));
    ap1 = cat8(*(const bf16x4*)(sP + iRow*LDP + 32 + 8*lg),
               *(const bf16x4*)(sP + iRow*LDP + 32 + 8*lg + 4));
    ap2 = cat8(*(const bf16x4*)(sP + iRow*LDP + 64 + 8*lg),
               *(const bf16x4*)(sP + iRow*LDP + 64 + 8*lg + 4));
    __builtin_amdgcn_s_setprio(1);
    #pragma unroll
    for (int nt = 0; nt < 4; ++nt) {
        const int d = 16*nt + lr;
        bf16x8 b0 = cat8(*(const bf16x4*)(sVt + d*LDV + 8*lg),
                         *(const bf16x4*)(sVt + d*LDV + 8*lg + 4));
        bf16x8 b1 = cat8(*(const bf16x4*)(sVt + d*LDV + 32 + 8*lg),
                         *(const bf16x4*)(sVt + d*LDV + 32 + 8*lg + 4));
        bf16x8 b2 = cat8(*(const bf16x4*)(sVt + d*LDV + 64 + 8*lg),
                         *(const bf16x4*)(sVt + d*LDV + 64 + 8*lg + 4));
        f32x4 a = {0.f,0.f,0.f,0.f};
        a = __builtin_amdgcn_mfma_f32_16x16x32_bf16(b0, ap0, a, 0, 0, 0);
        a = __builtin_amdgcn_mfma_f32_16x16x32_bf16(b1, ap1, a, 0, 0, 0);
        a = __builtin_amdgcn_mfma_f32_16x16x32_bf16(b2, ap2, a, 0, 0, 0);
        if (iRow < SEQ) {
            f32x4 o = { a[0]*inv, a[1]*inv, a[2]*inv, a[3]*inv };
            *(f32x4*)(out + base + iRow*DIM + 16*nt + 4*lg) = o;
        }
    }
    __builtin_amdgcn_s_setprio(0);
}

extern "C" void kernel_launch(void* const* d_in, const int* in_sizes, int n_in,
                              void* d_out, int out_size, void* d_ws, size_t ws_size,
                              hipStream_t stream) {
    const float* Q   = (const float*)d_in[0];
    const float* K   = (const float*)d_in[1];
    const float* V   = (const float*)d_in[2];
    const float* emb = (const float*)d_in[3];
    const int*   uc  = (const int*)d_in[4];
    float* out = (float*)d_out;

    const int nbh   = in_sizes[0] / (SEQ * DIM);   // 4096
    const int n_emb = in_sizes[3];                 // 163*64

    short* embw = (short*)d_ws;
    emb_cvt_kernel<<<(n_emb + 255) / 256, 256, 0, stream>>>(emb, embw, n_emb);

    const size_t smem = 32640;   // sVt 13056 + max(sK 13056, sP 19584)
    hipFuncSetAttribute(reinterpret_cast<const void*>(rpsa_kernel),
                        hipFuncAttributeMaxDynamicSharedMemorySize, (int)smem);
    rpsa_kernel<<<nbh, NT, smem, stream>>>(Q, K, V, embw, uc, out);
}

// Round 10
// 83.991 us; speedup vs baseline: 1.7436x; 1.7436x over previous
//
#include <hip/hip_runtime.h>
#include <hip/hip_bf16.h>

#define SEQ 81
#define DIM 64
#define NT  384          // 6 waves
#define NW  6
#define LDK 68           // sK row stride in shorts (136 B; 68%4==0 -> every b64 8B-aligned)
#define LDV 100          // sVt row stride in shorts (200 B; 100%4==0 -> 8B-aligned)
#define LDP 100          // sP row stride in shorts
// NOTE: stride MUST be a multiple of 4 shorts — 102 broke b64 alignment (R6-R9, ~1.8x slow).

typedef short bf16x8 __attribute__((ext_vector_type(8)));
typedef short bf16x4 __attribute__((ext_vector_type(4)));
typedef float f32x4  __attribute__((ext_vector_type(4)));

static constexpr float kS2 = 0.0520587716f;   // log2(e) / sqrt(768) — folded scale

__device__ __forceinline__ short f2bf(float f) {
    __hip_bfloat16 h = __float2bfloat16(f);
    return __builtin_bit_cast(short, h);
}
__device__ __forceinline__ float bf2f(short h) {
    unsigned u = ((unsigned)(unsigned short)h) << 16;
    return __builtin_bit_cast(float, u);
}
__device__ __forceinline__ bf16x8 cat8(bf16x4 a, bf16x4 b) {
    bf16x8 r;
    r[0]=a[0]; r[1]=a[1]; r[2]=a[2]; r[3]=a[3];
    r[4]=b[0]; r[5]=b[1]; r[6]=b[2]; r[7]=b[3];
    return r;
}

__global__ void emb_cvt_kernel(const float* __restrict__ in, short* __restrict__ out, int n) {
    int i = blockIdx.x * 256 + threadIdx.x;
    if (i < n) out[i] = f2bf(in[i]);
}

// Swapped-operand MFMAs: lane owns row i = 16w + (lane&15), and 4 consecutive
// {j|d} = 16nt + 4*(lane>>4) + r.  K staged LDS (2 barriers); emb staged bf16 in
// d_ws by prologue (21 KB, L1-resident); Qe prefetched pre-bar1, scattered post-bar2.
__global__ __launch_bounds__(NT, 8)
void rpsa_kernel(const float* __restrict__ Q, const float* __restrict__ K,
                 const float* __restrict__ V, const short* __restrict__ embw,
                 const int* __restrict__ ucp, float* __restrict__ out)
{
    extern __shared__ char smraw[];
    short* sVt = (short*)smraw;              // [64][100]  12800 B (V^T, bf16)
    short* sK  = (short*)(smraw + 12800);    // [96][68]   13056 B (bf16)
    short* sP  = (short*)(smraw + 12800);    // [96][100]  19200 B bias/P, overlays sK
    // total 32000 B -> 5 blocks/CU

    const int tid = threadIdx.x;
    const size_t base = (size_t)blockIdx.x * (SEQ * DIM);
    const int uc = ucp[0];
    const int w  = tid >> 6, L = tid & 63;
    const int lr = L & 15,  lg = L >> 4;
    const int iRow = 16*w + lr;              // lane's own row

    // ---- Q B-fragment from global, pre-scaled by log2e/sqrt(768) ----
    bf16x8 aq0, aq1;
    {
        const int qrow = (iRow < SEQ) ? iRow : (SEQ - 1);   // clamp pad lanes
        const float* qp = Q + base + qrow*DIM + 8*lg;
        const f32x4 q0 = *(const f32x4*)(qp);
        const f32x4 q1 = *(const f32x4*)(qp + 4);
        const f32x4 q2 = *(const f32x4*)(qp + 32);
        const f32x4 q3 = *(const f32x4*)(qp + 36);
        #pragma unroll
        for (int t = 0; t < 4; ++t) {
            aq0[t]   = f2bf(q0[t]*kS2);
            aq0[4+t] = f2bf(q1[t]*kS2);
            aq1[t]   = f2bf(q2[t]*kS2);
            aq1[4+t] = f2bf(q3[t]*kS2);
        }
    }

    // ---- stage K bf16 (rows >= 81 zeroed) ----
    for (int u = tid; u < 96 * DIM / 8; u += NT) {        // 2 iters
        const int row = u >> 3, so = (u & 7) * 8;
        bf16x4 lo = {0,0,0,0}, hi = {0,0,0,0};
        if (row < SEQ) {
            const f32x4 k0 = *(const f32x4*)(K + base + row*DIM + so);
            const f32x4 k1 = *(const f32x4*)(K + base + row*DIM + so + 4);
            #pragma unroll
            for (int t = 0; t < 4; ++t) { lo[t] = f2bf(k0[t]); hi[t] = f2bf(k1[t]); }
        }
        *(bf16x4*)(sK + row*LDK + so)     = lo;
        *(bf16x4*)(sK + row*LDK + so + 4) = hi;
    }
    // ---- stage V transposed (4x4 register transpose; cols j>=81 zeroed) ----
    {
        const int j4 = tid >> 4;          // 0..23
        const int d4 = tid & 15;          // 0..15
        f32x4 rw[4];
        #pragma unroll
        for (int e = 0; e < 4; ++e) {
            const int j = 4*j4 + e;
            rw[e] = (j < SEQ) ? *(const f32x4*)(V + base + j*DIM + 4*d4)
                              : (f32x4){0.f,0.f,0.f,0.f};
        }
        #pragma unroll
        for (int c = 0; c < 4; ++c) {
            const int d = 4*d4 + c;
            bf16x4 pv = { f2bf(rw[0][c]), f2bf(rw[1][c]), f2bf(rw[2][c]), f2bf(rw[3][c]) };
            *(bf16x4*)(sVt + d*LDV + 4*j4) = pv;
        }
    }

    // ---- Qe pass-1 prefetch (embw bf16, L1-resident; no LDS needed) ----
    // lane gets Qe[iRow][rel = 80 + 16nt2 + 4lg + r]; scatter deferred to post-bar2.
    bf16x4 qe[NW];
    #pragma unroll
    for (int nt2 = 0; nt2 < NW; ++nt2) {
        if (nt2 > w) continue;
        int erow = 80 + 16*nt2 + lr;
        if (erow > 2*SEQ) erow = 2*SEQ;          // clamp: affects only pad rows (i>80)
        bf16x8 e0 = *(const bf16x8*)(embw + erow*DIM + 8*lg);
        bf16x8 e1 = *(const bf16x8*)(embw + erow*DIM + 32 + 8*lg);
        f32x4 a = {0.f,0.f,0.f,0.f};
        a = __builtin_amdgcn_mfma_f32_16x16x32_bf16(e0, aq0, a, 0, 0, 0);
        a = __builtin_amdgcn_mfma_f32_16x16x32_bf16(e1, aq1, a, 0, 0, 0);
        bf16x4 p = { f2bf(a[0]), f2bf(a[1]), f2bf(a[2]), f2bf(a[3]) };
        qe[nt2] = p;
    }
    __syncthreads();   // bar1

    // ---- QK^T from sK: accs[nt][r] = S[iRow][j = 16nt + 4lg + r] ----
    f32x4 accs[NW] = {};
    const int ntEnd = uc ? w : (NW - 1);
    #pragma unroll
    for (int nt = 0; nt < NW; ++nt) {
        if (nt > ntEnd) continue;
        const int kr = 16*nt + lr;
        bf16x8 b0 = cat8(*(const bf16x4*)(sK + kr*LDK + 8*lg),
                         *(const bf16x4*)(sK + kr*LDK + 8*lg + 4));
        bf16x8 b1 = cat8(*(const bf16x4*)(sK + kr*LDK + 32 + 8*lg),
                         *(const bf16x4*)(sK + kr*LDK + 32 + 8*lg + 4));
        f32x4 a = accs[nt];
        a = __builtin_amdgcn_mfma_f32_16x16x32_bf16(b0, aq0, a, 0, 0, 0);
        a = __builtin_amdgcn_mfma_f32_16x16x32_bf16(b1, aq1, a, 0, 0, 0);
        accs[nt] = a;
    }
    __syncthreads();   // bar2: sK dead -> sP overlay live

    // ---- scatter prefetched pass-1 bias into sP (rows = own band -> race-free) ----
    #pragma unroll
    for (int nt2 = 0; nt2 < NW; ++nt2) {
        if (nt2 > w) continue;
        #pragma unroll
        for (int r = 0; r < 4; ++r) {
            const int j = 16*(w - nt2) + lr - 4*lg - r;   // j = iRow - (rel-80)
            if (j >= 0) sP[iRow*LDP + j] = qe[nt2][r];
        }
    }
    // ---- pass-0 (non-causal only): rel in [i,79], j = 80+i-rel > i ----
    if (!uc) {
        #pragma unroll
        for (int nt2 = 0; nt2 < NW - 1; ++nt2) {
            if (nt2 < w) continue;
            const int erow = 16*nt2 + lr;        // <= 79
            bf16x8 e0 = *(const bf16x8*)(embw + erow*DIM + 8*lg);
            bf16x8 e1 = *(const bf16x8*)(embw + erow*DIM + 32 + 8*lg);
            f32x4 a = {0.f,0.f,0.f,0.f};
            a = __builtin_amdgcn_mfma_f32_16x16x32_bf16(e0, aq0, a, 0, 0, 0);
            a = __builtin_amdgcn_mfma_f32_16x16x32_bf16(e1, aq1, a, 0, 0, 0);
            #pragma unroll
            for (int r = 0; r < 4; ++r) {
                const int rel = 16*nt2 + 4*lg + r;
                if (rel >= iRow) sP[iRow*LDP + (80 + iRow - rel)] = f2bf(a[r]);
            }
        }
    }
    // No barrier: each wave's bias slots are produced and consumed by the same wave.

    // ---- fused softmax (no max-subtraction; scores bounded) ----
    const int jmax = uc ? ((iRow < SEQ-1) ? iRow : SEQ-1) : (SEQ-1);
    float sum = 0.f;
    #pragma unroll
    for (int nt = 0; nt < NW; ++nt) {
        short* slot = sP + iRow*LDP + 16*nt + 4*lg;
        if (nt <= ntEnd) {
            bf16x4 bias = *(const bf16x4*)(slot);
            bf16x4 p;
            #pragma unroll
            for (int r = 0; r < 4; ++r) {
                const int j = 16*nt + 4*lg + r;
                const float x = accs[nt][r] + bf2f(bias[r]);
                const float e = (j <= jmax) ? exp2f(x) : 0.f;
                sum += e;
                p[r] = f2bf(e);
            }
            *(bf16x4*)(slot) = p;
        } else {
            *(bf16x4*)(slot) = (bf16x4){0,0,0,0};   // dead causal tiles -> P = 0
        }
    }
    sum += __shfl_xor(sum, 16);
    sum += __shfl_xor(sum, 32);
    const float inv = 1.f / sum;

    // ---- PV: lane gets O[iRow][d = 16nt + 4lg + r]; causal trims K-chunks ----
    // uc=1: P[iRow][j]==0 for j > 16w+15, so only (w>>1)+1 of 3 chunks contribute.
    const int nks = uc ? ((w >> 1) + 1) : 3;
    bf16x8 ap0, ap1, ap2;
    ap0 = cat8(*(const bf16x4*)(sP + iRow*LDP + 8*lg),
               *(const bf16x4*)(sP + iRow*LDP + 8*lg + 4));
    if (nks > 1)
        ap1 = cat8(*(const bf16x4*)(sP + iRow*LDP + 32 + 8*lg),
                   *(const bf16x4*)(sP + iRow*LDP + 32 + 8*lg + 4));
    if (nks > 2)
        ap2 = cat8(*(const bf16x4*)(sP + iRow*LDP + 64 + 8*lg),
                   *(const bf16x4*)(sP + iRow*LDP + 64 + 8*lg + 4));
    #pragma unroll
    for (int nt = 0; nt < 4; ++nt) {
        const int d = 16*nt + lr;
        f32x4 a = {0.f,0.f,0.f,0.f};
        bf16x8 b0 = cat8(*(const bf16x4*)(sVt + d*LDV + 8*lg),
                         *(const bf16x4*)(sVt + d*LDV + 8*lg + 4));
        a = __builtin_amdgcn_mfma_f32_16x16x32_bf16(b0, ap0, a, 0, 0, 0);
        if (nks > 1) {
            bf16x8 b1 = cat8(*(const bf16x4*)(sVt + d*LDV + 32 + 8*lg),
                             *(const bf16x4*)(sVt + d*LDV + 32 + 8*lg + 4));
            a = __builtin_amdgcn_mfma_f32_16x16x32_bf16(b1, ap1, a, 0, 0, 0);
        }
        if (nks > 2) {
            bf16x8 b2 = cat8(*(const bf16x4*)(sVt + d*LDV + 64 + 8*lg),
                             *(const bf16x4*)(sVt + d*LDV + 64 + 8*lg + 4));
            a = __builtin_amdgcn_mfma_f32_16x16x32_bf16(b2, ap2, a, 0, 0, 0);
        }
        if (iRow < SEQ) {
            f32x4 o = { a[0]*inv, a[1]*inv, a[2]*inv, a[3]*inv };
            *(f32x4*)(out + base + iRow*DIM + 16*nt + 4*lg) = o;
        }
    }
}

extern "C" void kernel_launch(void* const* d_in, const int* in_sizes, int n_in,
                              void* d_out, int out_size, void* d_ws, size_t ws_size,
                              hipStream_t stream) {
    const float* Q   = (const float*)d_in[0];
    const float* K   = (const float*)d_in[1];
    const float* V   = (const float*)d_in[2];
    const float* emb = (const float*)d_in[3];
    const int*   uc  = (const int*)d_in[4];
    float* out = (float*)d_out;

    const int nbh   = in_sizes[0] / (SEQ * DIM);   // 4096
    const int n_emb = in_sizes[3];                 // 163*64

    short* embw = (short*)d_ws;
    emb_cvt_kernel<<<(n_emb + 255) / 256, 256, 0, stream>>>(emb, embw, n_emb);

    const size_t smem = 32000;   // sVt 12800 + max(sK 13056, sP 19200)
    hipFuncSetAttribute(reinterpret_cast<const void*>(rpsa_kernel),
                        hipFuncAttributeMaxDynamicSharedMemorySize, (int)smem);
    rpsa_kernel<<<nbh, NT, smem, stream>>>(Q, K, V, embw, uc, out);
}